// Round 8
// baseline (369.314 us; speedup 1.0000x reference)
//
#include <hip/hip_runtime.h>
#include <hip/hip_bf16.h>
#include <math.h>

#define Bsz 64
#define T 32
#define H 768
#define E 8
#define NB 2
#define DFF 3072
#define NBEAM (Bsz * NB)   // 128
#define NT8MAX 24          // max 8-beam tiles: worst case sum ceil(cnt_e/8) = 23

// d_out layout (floats):
#define OUT_BS 3145728
#define OUT_ER 3145856
#define OUT_BI 3145984
#define OUT_IL 3146112

// ws layout (float units):
#define WS_LOGITS 0                 // 3*512 chunked partial logits
#define WS_BEAMW  1536              // 128
#define WS_SORT   1664              // 128 int
#define WS_T8E    1792              // 24 int
#define WS_T8B    1832              // 24 int
#define WS_T8C    1872              // 24 int
#define WS_XBF    2048              // x bf16: 786432 floats
#define WS_HBF    (2048 + 786432)   // h bf16: 6291456 floats
#define WS_W1S    (WS_HBF + 6291456)            // staged bf16 #1: 9437184 floats
#define WS_W2S    (WS_W1S + 9437184)            // staged bf16 #2: 9437184 floats
#define WS_NEED_ONE  ((size_t)(WS_W1S + 9437184) * 4)   // bytes: stage w2 only
#define WS_NEED_BOTH ((size_t)(WS_W2S + 9437184) * 4)   // bytes: stage both

typedef __attribute__((ext_vector_type(8))) short short8;
typedef __attribute__((ext_vector_type(4))) float f32x4;

__device__ __forceinline__ short8 cvt8(const float4 u, const float4 v) {
    union { short8 s; unsigned w[4]; } r;
    __hip_bfloat162 t;
    t = __float22bfloat162_rn(make_float2(u.x, u.y)); r.w[0] = *(unsigned*)&t;
    t = __float22bfloat162_rn(make_float2(u.z, u.w)); r.w[1] = *(unsigned*)&t;
    t = __float22bfloat162_rn(make_float2(v.x, v.y)); r.w[2] = *(unsigned*)&t;
    t = __float22bfloat162_rn(make_float2(v.z, v.w)); r.w[3] = *(unsigned*)&t;
    return r.s;
}

// async 16B global -> LDS (dest = uniform base + lane*16)
__device__ __forceinline__ void async16(void* lds, const void* g) {
    __builtin_amdgcn_global_load_lds(
        (const __attribute__((address_space(1))) void*)g,
        (__attribute__((address_space(3))) void*)lds, 16, 0, 0);
}

// ---------------------------------------------------------------------------
// Weight staging: fp32 row-major -> bf16 swizzled 8KB tiles, laid out per
// (expert, n-strip(128 rows), k-tile(32)) in the EXACT image the GEMM's
// W-DMA streams into LDS.  Slot s (16B) of a tile: row rloc = s>>2, stored
// pos p = s&3 holds source k-chunk p ^ ((rloc>>1)&3) (R5's proven
// conflict-free swizzle; identical to the direct kernel's wslot mapping
// since (s>>3)&3 == (row>>1)&3).  Reads are contiguous 32B/thread — the
// round-7/8 theory: the GEMM's 93us is HBM row-activation on 128B@12KB-
// stride weight reads (1.2-2.0 TB/s); contiguous streams run ~6 TB/s.
// One launch stages one matrix. grid.x = E*R*K/8/256 = 9216.
// ---------------------------------------------------------------------------
__global__ __launch_bounds__(256) void stage_w_kernel(
    const float* __restrict__ src, ushort* __restrict__ dst,
    int R, int K)
{
    const int kc8 = K >> 3;                       // 8-elem chunks per row
    const int chunk = blockIdx.x * 256 + threadIdx.x;   // < 2359296
    const int g    = chunk / kc8;                 // global row in [0, E*R)
    const int kidx = chunk - g * kc8;
    const int e    = g / R;
    const int row  = g - e * R;
    const float4 u = *(const float4*)(src + (size_t)chunk * 8);
    const float4 v = *(const float4*)(src + (size_t)chunk * 8 + 4);
    const short8 val = cvt8(u, v);
    const int kt    = kidx >> 2;
    const int pos   = kidx & 3;
    const int strip = row >> 7;
    const int rloc  = row & 127;
    const int p     = pos ^ ((rloc >> 1) & 3);
    const int s     = (rloc << 2) | p;
    const size_t tb = ((((size_t)e * (R >> 7) + strip) * (K >> 5)) + kt) * 4096;
    *(short8*)(dst + tb + s * 8) = val;
}

// ---------------------------------------------------------------------------
// Fused gate partials + x fp32->bf16. Grid (3 chunks, 64 batches).
// ---------------------------------------------------------------------------
__global__ __launch_bounds__(256) void gate_conv_kernel(
    const float* __restrict__ x, const float* __restrict__ gate_w,
    ushort* __restrict__ xb, float* __restrict__ logits_part)
{
    __shared__ float part[4][E];
    const int chunk = blockIdx.x, b = blockIdx.y;
    const int tid = threadIdx.x, wv = tid >> 6, lane = tid & 63;
    const int c = chunk * 256 + tid;
    const float* xp = x + (size_t)b * T * H + c;
    ushort* xo = xb + (size_t)b * T * H + c;
    float s = 0.f;
    #pragma unroll
    for (int t = 0; t < T; t += 2) {
        const float f0 = xp[t * H];
        const float f1 = xp[(t + 1) * H];
        s += f0; s += f1;
        __hip_bfloat162 t2 = __float22bfloat162_rn(make_float2(f0, f1));
        const unsigned u = *(const unsigned*)&t2;
        xo[t * H]       = (ushort)(u & 0xffff);
        xo[(t + 1) * H] = (ushort)(u >> 16);
    }
    const float avg = s * (1.0f / T);
    #pragma unroll
    for (int e = 0; e < E; ++e) {
        float p = avg * gate_w[e * H + c];
        #pragma unroll
        for (int off = 32; off; off >>= 1) p += __shfl_down(p, off, 64);
        if (lane == 0) part[wv][e] = p;
    }
    __syncthreads();
    if (tid < E) {
        float t = part[0][tid] + part[1][tid] + part[2][tid] + part[3][tid];
        logits_part[chunk * 512 + b * E + tid] = t;
    }
}

// ---------------------------------------------------------------------------
// Gating: softmax, top-2, outputs, importance loss, 8-beam expert tables.
// ---------------------------------------------------------------------------
__global__ __launch_bounds__(64) void gating_kernel(
    const float* __restrict__ logits_part, float* __restrict__ beam_w,
    int* __restrict__ sortb, int* __restrict__ t8e, int* __restrict__ t8b,
    int* __restrict__ t8c, float* __restrict__ dout)
{
    const int r = threadIdx.x;  // batch row 0..63
    float v[E];
    float mx = -1e30f;
    #pragma unroll
    for (int e = 0; e < E; ++e) {
        v[e] = logits_part[r * E + e] + logits_part[512 + r * E + e]
             + logits_part[1024 + r * E + e];
        mx = fmaxf(mx, v[e]);
    }
    float s = 0.f;
    #pragma unroll
    for (int e = 0; e < E; ++e) { v[e] = expf(v[e] - mx); s += v[e]; }
    const float inv = 1.0f / s;
    #pragma unroll
    for (int e = 0; e < E; ++e) v[e] *= inv;
    // top-2 (stable: lower index wins ties, matches jax.lax.top_k)
    float v0 = -1.f, v1 = -1.f; int i0 = 0, i1 = 0;
    #pragma unroll
    for (int e = 0; e < E; ++e) {
        if (v[e] > v0)      { v1 = v0; i1 = i0; v0 = v[e]; i0 = e; }
        else if (v[e] > v1) { v1 = v[e]; i1 = e; }
    }
    const int b0 = 2 * r, b1 = 2 * r + 1;
    dout[OUT_BS + b0] = v0;          dout[OUT_BS + b1] = v1;
    dout[OUT_ER + b0] = (float)i0;   dout[OUT_ER + b1] = (float)i1;
    dout[OUT_BI + b0] = (float)b0;   dout[OUT_BI + b1] = (float)b1;
    beam_w[b0] = v0;  beam_w[b1] = v1;
    // importance loss via 64-lane butterfly reductions
    float imp[E];
    #pragma unroll
    for (int e = 0; e < E; ++e) {
        float t = v[e];
        #pragma unroll
        for (int off = 1; off < 64; off <<= 1) t += __shfl_xor(t, off, 64);
        imp[e] = t;
    }
    if (r == 0) {
        float tot = 0.f;
        #pragma unroll
        for (int e = 0; e < E; ++e) tot += imp[e];
        const float mean = tot / E;
        float var = 0.f;
        #pragma unroll
        for (int e = 0; e < E; ++e) { float d = imp[e] - mean; var += d * d; }
        var /= (E - 1);
        dout[OUT_IL] = var / (mean * mean);
    }
    // expert-grouped sort via ballots (beams 2r even-mask, 2r+1 odd-mask)
    unsigned long long m0[E], m1[E];
    #pragma unroll
    for (int e = 0; e < E; ++e) {
        m0[e] = __ballot(i0 == e);
        m1[e] = __ballot(i1 == e);
    }
    int cnt[E], off[E];
    int a0 = 0;
    #pragma unroll
    for (int e = 0; e < E; ++e) {
        cnt[e] = __popcll(m0[e]) + __popcll(m1[e]);
        off[e] = a0; a0 += cnt[e];
    }
    const unsigned long long below = (r == 0) ? 0ull : ((1ull << r) - 1ull);
    const unsigned long long incl  = below | (1ull << r);
    const int pos0 = __popcll(m0[i0] & below) + __popcll(m1[i0] & below);
    const int pos1 = __popcll(m0[i1] & incl)  + __popcll(m1[i1] & below);
    sortb[off[i0] + pos0] = b0;
    sortb[off[i1] + pos1] = b1;
    // 8-beam tile table (single thread, tiny)
    if (r == 0) {
        int tiles[E];
        int used[NT8MAX];
        for (int t = 0; t < NT8MAX; ++t) used[t] = 0;
        #pragma unroll
        for (int e = 0; e < E; ++e) tiles[e] = (cnt[e] + 7) >> 3;
        #pragma unroll
        for (int e = 0; e < E; ++e) {
            const int k = tiles[e] < 3 ? tiles[e] : 3;
            for (int i = 0; i < k; ++i) {
                const int sl = 3 * e + i;
                t8e[sl] = e; t8b[sl] = off[e] + 8 * i;
                const int rem = cnt[e] - 8 * i;
                t8c[sl] = rem < 8 ? rem : 8;
                used[sl] = 1;
            }
        }
        int fs[NT8MAX]; int nf = 0;
        for (int round = 0; round < 3; ++round)
            for (int c = 0; c < E; ++c) {
                const int sl = 3 * c + round;
                if (!used[sl]) fs[nf++] = sl;
            }
        int fp = 0;
        for (int e = 0; e < E; ++e)
            for (int i = 3; i < tiles[e]; ++i) {
                const int sl = fs[fp++];
                t8e[sl] = e; t8b[sl] = off[e] + 8 * i;
                const int rem = cnt[e] - 8 * i;
                t8c[sl] = rem < 8 ? rem : 8;
                used[sl] = 1;
            }
        for (int t = 0; t < NT8MAX; ++t) if (!used[t]) t8c[t] = 0;
    }
}

// ---------------------------------------------------------------------------
// STAGED GEMM: identical loop skeleton to R5 (2-buffer, one __syncthreads
// per k-tile, proven 0-conflict swizzle, 48KB LDS -> 3 blocks/CU) with ONE
// variable changed: W comes from the pre-staged bf16 swizzled tile image
// via global_load_lds (contiguous 1KB/wave-instr) instead of strided fp32
// register loads + cvt8 in the hot loop.
// Tile: 256m (8 beams) x 128n, KTILE=32; 4 waves 2x2; acc[8][4].
// NSLICE>1: slices atomicAdd into zeroed output; slice k0==0 adds bias.
// ---------------------------------------------------------------------------
template <int KTOT, int RTOT, bool DO_GELU, int NSLICE>
__global__ __launch_bounds__(256, 2) void moe_ffn_staged(
    const ushort* __restrict__ Abf, int a_div,
    const ushort* __restrict__ Wst,
    const float* __restrict__ biasb,
    const int* __restrict__ sortb, const int* __restrict__ t8e,
    const int* __restrict__ t8b, const int* __restrict__ t8c,
    const float* __restrict__ beam_w,
    void* __restrict__ Obase)
{
    constexpr int KSPAN = KTOT / NSLICE;
    constexpr int KT    = KSPAN / 32;
    constexpr int NFRAG = 4;            // 128n / 32 per wave
    __shared__ __align__(16) ushort sA[2][256 * 32];   // 16 KB each
    __shared__ __align__(16) ushort sB[2][128 * 32];   // 8 KB each

    // XCD-chunked bijective swizzle; nwg = 576 for both launches (%8==0).
    const int nx  = gridDim.x;
    const int nwg = nx * gridDim.y;
    const int hw  = blockIdx.y * nx + blockIdx.x;
    const int q8  = nwg >> 3;
    const int lid = (hw & 7) * q8 + (hw >> 3);
    const int tile  = lid % NT8MAX;
    const int rr    = lid / NT8MAX;
    const int strip = rr % nx;
    const int k0    = (rr / nx) * KSPAN;

    const int cnt  = t8c[tile];
    if (cnt == 0) return;
    const int e    = t8e[tile];
    const int base = t8b[tile];
    const int tid  = threadIdx.x;
    const int wv   = tid >> 6;
    const int lane = tid & 63;
    const int quad = lane >> 4;
    const int l16  = lane & 15;
    const int mh   = (wv & 1) * 128;
    const int nh   = (wv >> 1) * 64;
    const int n0   = strip * 128;

    int bm[8];
    #pragma unroll
    for (int s = 0; s < 8; ++s) bm[s] = sortb[base + (s < cnt ? s : cnt - 1)];

    // A DMA sources (R5 pattern): slot s=(wv*4+jj)*64+lane:
    // row=s>>2, chunk c=(s&3)^((s>>3)&3)
    const ushort* aseg[4];
    #pragma unroll
    for (int jj = 0; jj < 4; ++jj) {
        const int s = (wv * 4 + jj) * 64 + lane;
        const int r = s >> 2;
        const int c = (s & 3) ^ ((s >> 3) & 3);
        aseg[jj] = Abf + (size_t)(bm[r >> 5] / a_div) * T * KTOT
                 + (size_t)(r & 31) * KTOT + c * 8 + k0;
    }
    // W DMA sources: staged tiles are the exact LDS image -> contiguous.
    const ushort* wseg[2];
    {
        const ushort* wtile0 = Wst
            + ((((size_t)e * (RTOT >> 7) + strip) * (KTOT >> 5)) + (k0 >> 5)) * 4096;
        #pragma unroll
        for (int jj = 0; jj < 2; ++jj)
            wseg[jj] = wtile0 + ((wv * 2 + jj) * 64 + lane) * 8;
    }

    // fragment read offsets (proven conflict-free): pos = quad ^ f(r),
    // f(r) = (r>>1)&3 -> fx = (l16>>1)&3
    const int fx = (l16 >> 1) & 3;
    int aoff[8], boff[NFRAG];
    #pragma unroll
    for (int mt = 0; mt < 8; ++mt)
        aoff[mt] = (mh + mt * 16 + l16) * 32 + ((quad ^ fx) * 8);
    #pragma unroll
    for (int nt = 0; nt < NFRAG; ++nt)
        boff[nt] = (nh + nt * 16 + l16) * 32 + ((quad ^ fx) * 8);

    // prologue: tile 0 fully in flight (A + W DMA)
    #pragma unroll
    for (int jj = 0; jj < 4; ++jj)
        async16((char*)sA[0] + (wv * 4 + jj) * 1024, aseg[jj]);
    #pragma unroll
    for (int jj = 0; jj < 2; ++jj)
        async16((char*)sB[0] + (wv * 2 + jj) * 1024, wseg[jj]);

    f32x4 acc[8][NFRAG];
    #pragma unroll
    for (int mt = 0; mt < 8; ++mt)
        #pragma unroll
        for (int nt = 0; nt < NFRAG; ++nt) acc[mt][nt] = {0.f, 0.f, 0.f, 0.f};

    for (int kt = 0; kt < KT; ++kt) {
        const int p = kt & 1;
        __syncthreads();   // drains DMA(kt); all readers of buf(1-p) are past
        if (kt + 1 < KT) { // prefetch NEXT tile into other buffer
            #pragma unroll
            for (int jj = 0; jj < 4; ++jj)
                async16((char*)sA[1 - p] + (wv * 4 + jj) * 1024,
                        aseg[jj] + (kt + 1) * 32);
            #pragma unroll
            for (int jj = 0; jj < 2; ++jj)
                async16((char*)sB[1 - p] + (wv * 2 + jj) * 1024,
                        wseg[jj] + (size_t)(kt + 1) * 4096);
        }
        // compute(kt): one 16x16x32 MFMA per (mt,nt)
        short8 wf[NFRAG];
        #pragma unroll
        for (int nt = 0; nt < NFRAG; ++nt)
            wf[nt] = *(const short8*)(sB[p] + boff[nt]);
        #pragma unroll
        for (int mt = 0; mt < 8; ++mt) {
            const short8 af = *(const short8*)(sA[p] + aoff[mt]);
            #pragma unroll
            for (int nt = 0; nt < NFRAG; ++nt)
                acc[mt][nt] = __builtin_amdgcn_mfma_f32_16x16x32_bf16(
                    af, wf[nt], acc[mt][nt], 0, 0, 0);
        }
    }

    // epilogue
    #pragma unroll
    for (int nt = 0; nt < NFRAG; ++nt) {
        const int n = n0 + nh + nt * 16 + l16;
        const float bias = biasb[(size_t)e * RTOT + n];
        #pragma unroll
        for (int mt = 0; mt < 8; ++mt) {
            const int rowb = mh + mt * 16 + quad * 4;
            const int s = rowb >> 5;
            if (s >= cnt) continue;
            const int b = bm[s];
            const float scale = DO_GELU ? 1.0f : beam_w[b];
            #pragma unroll
            for (int r = 0; r < 4; ++r) {
                const int t = (rowb + r) & 31;
                const size_t idx = (size_t)b * T * RTOT + (size_t)t * RTOT + n;
                if (DO_GELU) {
                    float vv = acc[mt][nt][r] + bias;
                    vv = 0.5f * vv * (1.0f + erff(vv * 0.70710678118654752f));
                    ((__hip_bfloat16*)Obase)[idx] = __float2bfloat16(vv);
                } else {
                    float vv = acc[mt][nt][r] + ((k0 == 0) ? bias : 0.f);
                    atomicAdd((float*)Obase + idx, vv * scale);
                }
            }
        }
    }
}

// ---------------------------------------------------------------------------
// Fallback direct-W GEMM (R5 kernel, verbatim) — used when ws can't hold
// the staged weights.
// ---------------------------------------------------------------------------
template <int KTOT, int NTILE, bool DO_GELU, int NSLICE>
__global__ __launch_bounds__(256, 2) void moe_ffn_direct(
    const ushort* __restrict__ Abf, int a_div,
    const float* __restrict__ Wf32, int w_rows,
    const float* __restrict__ biasb,
    const int* __restrict__ sortb, const int* __restrict__ t8e,
    const int* __restrict__ t8b, const int* __restrict__ t8c,
    const float* __restrict__ beam_w,
    void* __restrict__ Obase)
{
    constexpr int KSPAN = KTOT / NSLICE;
    constexpr int KT    = KSPAN / 32;
    constexpr int NFRAG = NTILE / 32;
    constexpr int WSLOT = NTILE / 64;
    __shared__ __align__(16) ushort sA[2][256 * 32];
    __shared__ __align__(16) ushort sB[2][NTILE * 32];

    const int nx  = gridDim.x;
    const int nwg = nx * gridDim.y;
    const int hw  = blockIdx.y * nx + blockIdx.x;
    const int q8  = nwg >> 3;
    const int lid = (hw & 7) * q8 + (hw >> 3);
    const int tile  = lid % NT8MAX;
    const int rr    = lid / NT8MAX;
    const int strip = rr % nx;
    const int k0    = (rr / nx) * KSPAN;

    const int cnt  = t8c[tile];
    if (cnt == 0) return;
    const int e    = t8e[tile];
    const int base = t8b[tile];
    const int tid  = threadIdx.x;
    const int wv   = tid >> 6;
    const int lane = tid & 63;
    const int quad = lane >> 4;
    const int l16  = lane & 15;
    const int mh   = (wv & 1) * 128;
    const int nh   = (wv >> 1) * (NTILE / 2);
    const int n0   = strip * NTILE;

    int bm[8];
    #pragma unroll
    for (int s = 0; s < 8; ++s) bm[s] = sortb[base + (s < cnt ? s : cnt - 1)];

    const ushort* aseg[4];
    #pragma unroll
    for (int jj = 0; jj < 4; ++jj) {
        const int s = (wv * 4 + jj) * 64 + lane;
        const int r = s >> 2;
        const int c = (s & 3) ^ ((s >> 3) & 3);
        aseg[jj] = Abf + (size_t)(bm[r >> 5] / a_div) * T * KTOT
                 + (size_t)(r & 31) * KTOT + c * 8 + k0;
    }
    const float* wseg[WSLOT];
    int wslot[WSLOT];
    #pragma unroll
    for (int jj = 0; jj < WSLOT; ++jj) {
        const int s = jj * 256 + tid;
        const int r = s >> 2;
        const int c = (s & 3) ^ ((s >> 3) & 3);
        wseg[jj] = Wf32 + (size_t)e * w_rows * KTOT + (size_t)(n0 + r) * KTOT
                 + c * 8 + k0;
        wslot[jj] = s * 8;
    }

    const int fx = (l16 >> 1) & 3;
    int aoff[8], boff[NFRAG];
    #pragma unroll
    for (int mt = 0; mt < 8; ++mt)
        aoff[mt] = (mh + mt * 16 + l16) * 32 + ((quad ^ fx) * 8);
    #pragma unroll
    for (int nt = 0; nt < NFRAG; ++nt)
        boff[nt] = (nh + nt * 16 + l16) * 32 + ((quad ^ fx) * 8);

    float4 wr[WSLOT][2];
    #pragma unroll
    for (int jj = 0; jj < WSLOT; ++jj) {
        wr[jj][0] = *(const float4*)(wseg[jj]);
        wr[jj][1] = *(const float4*)(wseg[jj] + 4);
    }
    #pragma unroll
    for (int jj = 0; jj < 4; ++jj)
        async16((char*)sA[0] + (wv * 4 + jj) * 1024, aseg[jj]);

    f32x4 acc[8][NFRAG];
    #pragma unroll
    for (int mt = 0; mt < 8; ++mt)
        #pragma unroll
        for (int nt = 0; nt < NFRAG; ++nt) acc[mt][nt] = {0.f, 0.f, 0.f, 0.f};

    for (int kt = 0; kt < KT; ++kt) {
        const int p = kt & 1;
        #pragma unroll
        for (int jj = 0; jj < WSLOT; ++jj)
            *(short8*)(sB[p] + wslot[jj]) = cvt8(wr[jj][0], wr[jj][1]);
        __syncthreads();
        if (kt + 1 < KT) {
            const int kn = (kt + 1) * 32;
            #pragma unroll
            for (int jj = 0; jj < 4; ++jj)
                async16((char*)sA[1 - p] + (wv * 4 + jj) * 1024, aseg[jj] + kn);
            #pragma unroll
            for (int jj = 0; jj < WSLOT; ++jj) {
                wr[jj][0] = *(const float4*)(wseg[jj] + kn);
                wr[jj][1] = *(const float4*)(wseg[jj] + kn + 4);
            }
        }
        short8 wf[NFRAG];
        #pragma unroll
        for (int nt = 0; nt < NFRAG; ++nt)
            wf[nt] = *(const short8*)(sB[p] + boff[nt]);
        #pragma unroll
        for (int mt = 0; mt < 8; ++mt) {
            const short8 af = *(const short8*)(sA[p] + aoff[mt]);
            #pragma unroll
            for (int nt = 0; nt < NFRAG; ++nt)
                acc[mt][nt] = __builtin_amdgcn_mfma_f32_16x16x32_bf16(
                    af, wf[nt], acc[mt][nt], 0, 0, 0);
        }
    }

    #pragma unroll
    for (int nt = 0; nt < NFRAG; ++nt) {
        const int n = n0 + nh + nt * 16 + l16;
        const float bias = biasb[(size_t)e * w_rows + n];
        #pragma unroll
        for (int mt = 0; mt < 8; ++mt) {
            const int rowb = mh + mt * 16 + quad * 4;
            const int s = rowb >> 5;
            if (s >= cnt) continue;
            const int b = bm[s];
            const float scale = DO_GELU ? 1.0f : beam_w[b];
            #pragma unroll
            for (int r = 0; r < 4; ++r) {
                const int t = (rowb + r) & 31;
                const size_t idx = (size_t)b * T * w_rows + (size_t)t * w_rows + n;
                if (DO_GELU) {
                    float vv = acc[mt][nt][r] + bias;
                    vv = 0.5f * vv * (1.0f + erff(vv * 0.70710678118654752f));
                    ((__hip_bfloat16*)Obase)[idx] = __float2bfloat16(vv);
                } else {
                    float vv = acc[mt][nt][r] + ((k0 == 0) ? bias : 0.f);
                    atomicAdd((float*)Obase + idx, vv * scale);
                }
            }
        }
    }
}

extern "C" void kernel_launch(void* const* d_in, const int* in_sizes, int n_in,
                              void* d_out, int out_size, void* d_ws, size_t ws_size,
                              hipStream_t stream)
{
    const float* x      = (const float*)d_in[0];
    const float* gate_w = (const float*)d_in[1];
    const float* w1     = (const float*)d_in[2];
    const float* b1     = (const float*)d_in[3];
    const float* w2     = (const float*)d_in[4];
    const float* b2     = (const float*)d_in[5];
    float* out = (float*)d_out;
    float* ws  = (float*)d_ws;

    float*  logits = ws + WS_LOGITS;
    float*  beam_w = ws + WS_BEAMW;
    int*    sortb  = (int*)(ws + WS_SORT);
    int*    t8e    = (int*)(ws + WS_T8E);
    int*    t8b    = (int*)(ws + WS_T8B);
    int*    t8c    = (int*)(ws + WS_T8C);
    ushort* x_bf   = (ushort*)(ws + WS_XBF);
    ushort* h_bf   = (ushort*)(ws + WS_HBF);
    ushort* w1s    = (ushort*)(ws + WS_W1S);
    ushort* w2s    = (ushort*)(ws + WS_W2S);

    // zero the main output region (split-K GEMM2 accumulates atomically)
    hipMemsetAsync(out, 0, (size_t)NBEAM * T * H * sizeof(float), stream);

    // tiered staging by available workspace:
    //   both (104 MB) > w2-only (66 MB; GEMM2 is the dominant dispatch) > none
    const int mode = (ws_size >= WS_NEED_BOTH) ? 2
                   : (ws_size >= WS_NEED_ONE)  ? 1 : 0;
    if (mode == 2) {
        stage_w_kernel<<<9216, 256, 0, stream>>>(w1, w1s, DFF, H);
        stage_w_kernel<<<9216, 256, 0, stream>>>(w2, w2s, H, DFF);
    } else if (mode == 1) {
        stage_w_kernel<<<9216, 256, 0, stream>>>(w2, w1s, H, DFF); // w2 -> slot1
    }
    gate_conv_kernel<<<dim3(3, Bsz), 256, 0, stream>>>(x, gate_w, x_bf, logits);
    gating_kernel<<<1, 64, 0, stream>>>(logits, beam_w, sortb, t8e, t8b, t8c, out);

    // GEMM1 + GELU: K=768, rows=DFF, 24 strips x 24 tiles = 576 wg
    if (mode == 2)
        moe_ffn_staged<H, DFF, true, 1><<<dim3(DFF / 128, NT8MAX), 256, 0, stream>>>(
            x_bf, NB, w1s, b1, sortb, t8e, t8b, t8c, beam_w, (void*)h_bf);
    else
        moe_ffn_direct<H, 128, true, 1><<<dim3(DFF / 128, NT8MAX), 256, 0, stream>>>(
            x_bf, NB, w1, DFF, b1, sortb, t8e, t8b, t8c, beam_w, (void*)h_bf);

    // GEMM2 + scale: K=3072 split 4x768, rows=H, 6 strips x 96 = 576 wg
    if (mode >= 1) {
        const ushort* w2stage = (mode == 2) ? w2s : w1s;
        moe_ffn_staged<DFF, H, false, 4><<<dim3(H / 128, NT8MAX * 4), 256, 0, stream>>>(
            h_bf, 1, w2stage, b2, sortb, t8e, t8b, t8c, beam_w, out);
    } else {
        moe_ffn_direct<DFF, 128, false, 4><<<dim3(H / 128, NT8MAX * 4), 256, 0, stream>>>(
            h_bf, 1, w2, H, b2, sortb, t8e, t8b, t8c, beam_w, out);
    }
}